// Round 3
// baseline (1160.861 us; speedup 1.0000x reference)
//
#include <hip/hip_runtime.h>
#include <stdint.h>

// ---------------- problem constants ----------------
#define B_N   1024
#define D_N   512
#define C_N   50000
#define K_N   3

#define SLABS 1568                  // 128-row slabs (32 padded classes each); mult of 8
#define NROWS (SLABS * 128)         // 200704 padded weight rows (4 rows per class)
#define GRID_G (SLABS * 8)          // 12544 gemm blocks (8 batch tiles per slab)

#define S_SCALE 50.0f
#define COS_M   0.8775825619f       // cos(0.5)
#define SIN_M   0.4794255386f       // sin(0.5)
#define EPS_C   1e-7f

typedef __bf16 bf16_t;
typedef bf16_t bf16x8 __attribute__((ext_vector_type(8)));
typedef float  f32x4  __attribute__((ext_vector_type(4)));

__device__ __forceinline__ float wave_reduce_sum(float v) {
#pragma unroll
    for (int m = 1; m < 64; m <<= 1) v += __shfl_xor(v, m, 64);
    return v;
}

__device__ __forceinline__ void async_copy16(const void* g, void* l) {
    __builtin_amdgcn_global_load_lds(
        (const __attribute__((address_space(1))) void*)g,
        (__attribute__((address_space(3))) void*)l,
        16, 0, 0);
}

// ---------------- fused prepass: l2-normalize emb + weight rows -> bf16 ----------------
// one wave per row. Weight row r -> padded row (r/3)*4 + r%3 (subcenter 3 = garbage pad,
// never read by the epilogue). nt loads: fp32 inputs are read-once, keep L3 for Wn.
__global__ void k_norm(const float* __restrict__ emb, const float* __restrict__ w,
                       bf16_t* __restrict__ En, bf16_t* __restrict__ Wn) {
    const int row  = blockIdx.x * 4 + (threadIdx.x >> 6);
    const int lane = threadIdx.x & 63;
    const float* src;
    bf16_t*      dst;
    if (row < B_N) {
        src = emb + (size_t)row * D_N;
        dst = En  + (size_t)row * D_N;
    } else {
        const int r = row - B_N;
        src = w  + (size_t)r * D_N;
        dst = Wn + ((size_t)(r / 3) * 4 + (r % 3)) * D_N;
    }
    const f32x4* p = (const f32x4*)(src + lane * 8);
    f32x4 a = __builtin_nontemporal_load(p);
    f32x4 b = __builtin_nontemporal_load(p + 1);
    float s = a[0]*a[0] + a[1]*a[1] + a[2]*a[2] + a[3]*a[3]
            + b[0]*b[0] + b[1]*b[1] + b[2]*b[2] + b[3]*b[3];
    s = wave_reduce_sum(s);
    const float sc = 1.0f / fmaxf(sqrtf(s), 1e-12f);
    bf16x8 o;
    o[0] = (bf16_t)(a[0]*sc); o[1] = (bf16_t)(a[1]*sc);
    o[2] = (bf16_t)(a[2]*sc); o[3] = (bf16_t)(a[3]*sc);
    o[4] = (bf16_t)(b[0]*sc); o[5] = (bf16_t)(b[1]*sc);
    o[6] = (bf16_t)(b[2]*sc); o[7] = (bf16_t)(b[3]*sc);
    *(bf16x8*)(dst + lane * 8) = o;   // cached store: GEMM re-reads from L3
}

// ---------------- GEMM: R1 structure + XCD swizzle + LDS union + nt stores ----------------
// 128 rows x 128 batch block, 2x2 waves of 64x64, 16x16x32 bf16 MFMA.
// Row = class*4 + subcenter (pad row 3 never read): lane's 4 acc regs of one
// 16x16 tile = the 4 subcenters of ONE class -> max in-register.
__global__ __launch_bounds__(256) void k_gemm(const bf16_t* __restrict__ Wn,
                                              const bf16_t* __restrict__ En,
                                              const int*    __restrict__ labels,
                                              float*        __restrict__ out) {
    __shared__ union {
        struct { bf16_t W[128][32]; bf16_t E[128][32]; } st;  // 16.0 KB staging
        float so[128][33];                                    // 16.9 KB epilogue
    } sh;

    const int tid  = threadIdx.x;
    const int wave = tid >> 6, lane = tid & 63;
    const int wr = wave >> 1, wc = wave & 1;     // 2x2 wave grid, 64x64 each
    const int col = lane & 15, quad = lane >> 4;

    // XCD swizzle (R2-proven): all 8 batch-tile blocks of a slab share l&7
    // -> same XCD, temporally adjacent -> weight slab served from that L2.
    const int l  = blockIdx.x;
    const int r8 = l & 7, g = l >> 3;
    const int s  = (g >> 3) * 8 + r8;            // slab id
    const int bt = g & 7;                        // batch tile
    const size_t n0 = (size_t)s * 128;
    const int c0 = s * 32;
    const int b0 = bt * 128;

    f32x4 acc[4][4] = {};

    const int srow = lane >> 2, schunk = (lane & 3) * 8;

    for (int kk = 0; kk < D_N; kk += 32) {
        __syncthreads();
#pragma unroll
        for (int i = 0; i < 2; ++i) {
            const int rb = i * 64 + wave * 16;   // wave-uniform slab base
            async_copy16(Wn + (n0 + rb + srow) * D_N + kk + schunk, &sh.st.W[rb][0]);
            async_copy16(En + (size_t)(b0 + rb + srow) * D_N + kk + schunk, &sh.st.E[rb][0]);
        }
        __syncthreads();

        bf16x8 af[4], bfr[4];
#pragma unroll
        for (int t = 0; t < 4; ++t) {
            af[t]  = *(const bf16x8*)&sh.st.W[wr * 64 + t * 16 + col][quad * 8];
            bfr[t] = *(const bf16x8*)&sh.st.E[wc * 64 + t * 16 + col][quad * 8];
        }
#pragma unroll
        for (int ti = 0; ti < 4; ++ti)
#pragma unroll
            for (int tj = 0; tj < 4; ++tj)
                acc[ti][tj] = __builtin_amdgcn_mfma_f32_16x16x32_bf16(
                    af[ti], bfr[tj], acc[ti][tj], 0, 0, 0);
    }

    // ---- epilogue: in-register subcenter max, margin, LDS transpose, nt store ----
    int lab[4];
#pragma unroll
    for (int tj = 0; tj < 4; ++tj) lab[tj] = labels[b0 + wc * 64 + tj * 16 + col];

    __syncthreads();   // all staging reads done; union may be overwritten

#pragma unroll
    for (int ti = 0; ti < 4; ++ti) {
        const int c_local = wr * 16 + ti * 4 + quad;   // 0..31
        const int c       = c0 + c_local;
#pragma unroll
        for (int tj = 0; tj < 4; ++tj) {
            float v = fmaxf(fmaxf(acc[ti][tj][0], acc[ti][tj][1]), acc[ti][tj][2]);
            if (c == lab[tj]) {
                float x = fminf(fmaxf(v, -1.0f + EPS_C), 1.0f - EPS_C);
                v = x * COS_M - sqrtf(fmaxf(1.0f - x * x, 0.0f)) * SIN_M;
            }
            sh.so[wc * 64 + tj * 16 + col][c_local] = S_SCALE * v;
        }
    }
    __syncthreads();

    // coalesced nt write-out: 128 batches x 32 classes (128 B contiguous per row)
    const int row  = tid >> 1;
    const int half = tid & 1;
    const size_t gbase = (size_t)(b0 + row) * C_N;
#pragma unroll
    for (int q = 0; q < 4; ++q) {
        const int ci = half * 16 + q * 4;
        const int c  = c0 + ci;
        if (c < C_N) {
            f32x4 o = { sh.so[row][ci], sh.so[row][ci + 1],
                        sh.so[row][ci + 2], sh.so[row][ci + 3] };
            __builtin_nontemporal_store(o, (f32x4*)(out + gbase + c));
        }
    }
}

// ---------------- fallback path (ws too small) ----------------
__global__ void k_fb_norms(const float* __restrict__ emb, const float* __restrict__ w,
                           float* __restrict__ einv, float* __restrict__ winv) {
    const int row  = blockIdx.x * 4 + (threadIdx.x >> 6);
    const int lane = threadIdx.x & 63;
    if (row >= B_N + C_N * K_N) return;
    const float* src = (row < B_N) ? (emb + (size_t)row * D_N)
                                   : (w + (size_t)(row - B_N) * D_N);
    const float4* p = (const float4*)(src + lane * 8);
    float4 a = p[0], b = p[1];
    float s = a.x*a.x + a.y*a.y + a.z*a.z + a.w*a.w
            + b.x*b.x + b.y*b.y + b.z*b.z + b.w*b.w;
    s = wave_reduce_sum(s);
    if (lane == 0) {
        float sc = 1.0f / fmaxf(sqrtf(s), 1e-12f);
        if (row < B_N) einv[row] = sc; else winv[row - B_N] = sc;
    }
}

__global__ void k_fb_gemm(const float* __restrict__ emb, const float* __restrict__ w,
                          const int* __restrict__ labels, const float* __restrict__ einv,
                          const float* __restrict__ winv, float* __restrict__ out) {
    const int b = blockIdx.x;
    const int c = blockIdx.y * 256 + threadIdx.x;
    if (c >= C_N) return;
    const float4* e4 = (const float4*)(emb + (size_t)b * D_N);
    const float es = einv[b];
    float best = -1e30f;
    for (int k = 0; k < K_N; ++k) {
        const float4* w4 = (const float4*)(w + ((size_t)c * K_N + k) * D_N);
        float dot = 0.0f;
#pragma unroll 4
        for (int d = 0; d < D_N / 4; ++d) {
            float4 a = e4[d], bb = w4[d];
            dot += a.x*bb.x + a.y*bb.y + a.z*bb.z + a.w*bb.w;
        }
        dot *= es * winv[c * K_N + k];
        best = fmaxf(best, dot);
    }
    if (c == labels[b]) {
        float x = fminf(fmaxf(best, -1.0f + EPS_C), 1.0f - EPS_C);
        best = x * COS_M - sqrtf(fmaxf(1.0f - x * x, 0.0f)) * SIN_M;
    }
    out[(size_t)b * C_N + c] = S_SCALE * best;
}

// ---------------- launch ----------------
extern "C" void kernel_launch(void* const* d_in, const int* in_sizes, int n_in,
                              void* d_out, int out_size, void* d_ws, size_t ws_size,
                              hipStream_t stream) {
    const float* emb    = (const float*)d_in[0];
    const int*   labels = (const int*)d_in[1];
    const float* weight = (const float*)d_in[2];
    float*       out    = (float*)d_out;

    const size_t offW = (size_t)1 << 20;                     // 1 MB for En
    const size_t need = offW + (size_t)NROWS * D_N * 2;      // + bf16 weights (~206 MB)
    if (ws_size >= need) {
        bf16_t* En = (bf16_t*)d_ws;
        bf16_t* Wn = (bf16_t*)((char*)d_ws + offW);
        k_norm<<<(B_N + C_N * K_N) / 4, 256, 0, stream>>>(emb, weight, En, Wn);
        k_gemm<<<GRID_G, 256, 0, stream>>>(Wn, En, labels, out);
    } else {
        float* einv = (float*)d_ws;
        float* winv = einv + B_N;
        k_fb_norms<<<(B_N + C_N * K_N + 3) / 4, 256, 0, stream>>>(emb, weight, einv, winv);
        k_fb_gemm<<<dim3(B_N, (C_N + 255) / 256), 256, 0, stream>>>(emb, weight, labels,
                                                                    einv, winv, out);
    }
}